// Round 14
// baseline (494.762 us; speedup 1.0000x reference)
//
#include <hip/hip_runtime.h>
#include <hip/hip_bf16.h>
#include <stdint.h>

// ---------- helpers ----------
typedef __attribute__((ext_vector_type(8))) short bf16x8;
typedef __attribute__((ext_vector_type(4))) float f32x4;

__device__ __forceinline__ float bf16lo_to_f(uint32_t u) { return __uint_as_float(u << 16); }
__device__ __forceinline__ float bf16hi_to_f(uint32_t u) { return __uint_as_float(u & 0xffff0000u); }
__device__ __forceinline__ uint16_t f_to_bf16(float f) {
    uint32_t u = __float_as_uint(f);
    uint32_t r = u + 0x7fff + ((u >> 16) & 1);   // round-to-nearest-even
    return (uint16_t)(r >> 16);
}

// Layouts:
//  Txb : bf16 [N][640]  -- GEMM A operand ONLY (write-only in lhat, nontemporal)
//  Txq : int8 [N+1][640] -- gather + recurrence state; row slot = 128B = 1 line
//  mS  : f32 [5][N+1]  dis[n]*rowscale (gather weights); sentinel row N = 0
//  scq : f32 [5][N+1]  plain rowscale (self diag/prev dequant)
//  csr : u16 [E + 8N]  col only; per-node region padded to x8 with sentinel N

#define BINCH 4096

__global__ void __launch_bounds__(256) k_bhist(const int* __restrict__ row,
                                               int* __restrict__ bhist, int E) {
    __shared__ int sh[256];
    int t = threadIdx.x;
    sh[t] = 0;
    __syncthreads();
    int stride = gridDim.x * blockDim.x;
    for (int e = blockIdx.x * blockDim.x + t; e < E; e += stride)
        atomicAdd(&sh[row[e] >> 8], 1);
    __syncthreads();
    if (sh[t]) atomicAdd(&bhist[t], sh[t]);
}

// scan bucket counts -> gbase/gcur; also zero mS sentinels
__global__ void k_bscan(const int* __restrict__ bhist, int* __restrict__ gbase,
                        int* __restrict__ gcur, float* __restrict__ mS, int nbk, int N) {
    __shared__ int sh[256];
    int t = threadIdx.x;
    int v = t < nbk ? bhist[t] : 0;
    sh[t] = v;
    __syncthreads();
    for (int o = 1; o < 256; o <<= 1) {
        int u = (t >= o) ? sh[t - o] : 0;
        __syncthreads();
        sh[t] += u;
        __syncthreads();
    }
    gbase[t] = sh[t] - v;
    gcur[t] = sh[t] - v;
    if (t == 255) gbase[256] = sh[255];
    if (t < 5) mS[(size_t)t * (N + 1) + N] = 0.f;
}

// bin edges into bucket-sorted list; entry = (row&255) | (col<<8)
__global__ void __launch_bounds__(256) k_bin(const int* __restrict__ row,
        const int* __restrict__ col, int* __restrict__ gcur,
        uint32_t* __restrict__ bout, int E) {
    __shared__ uint32_t stage[BINCH];
    __shared__ int hist[256], hscan[256], hcur[256], gofs[256];
    int t = threadIdx.x;
    int e0 = blockIdx.x * BINCH;
    int ecnt = min(BINCH, E - e0);
    hist[t] = 0;
    __syncthreads();
    for (int i = t; i < ecnt; i += 256)
        atomicAdd(&hist[row[e0 + i] >> 8], 1);
    __syncthreads();
    int v = hist[t];
    hscan[t] = v;
    __syncthreads();
    for (int o = 1; o < 256; o <<= 1) {
        int u = (t >= o) ? hscan[t - o] : 0;
        __syncthreads();
        hscan[t] += u;
        __syncthreads();
    }
    hcur[t] = hscan[t] - v;
    __syncthreads();
    for (int i = t; i < ecnt; i += 256) {
        int r = row[e0 + i];
        int p = atomicAdd(&hcur[r >> 8], 1);
        stage[p] = (uint32_t)(r & 255) | ((uint32_t)col[e0 + i] << 8);
    }
    __syncthreads();
    if (v > 0) gofs[t] = atomicAdd(&gcur[t], v);
    __syncthreads();
    for (int i = t; i < ecnt; i += 256) {
        int lo = 0, hi = 255;
        while (lo < hi) { int mid = (lo + hi) >> 1; if (hscan[mid] > i) hi = mid; else lo = mid + 1; }
        int b = lo;
        int local = i - (hscan[b] - hist[b]);
        bout[gofs[b] + local] = stage[i];
    }
}

// per-node degree from bucket lists, FUSED with padded per-block sum (psum)
__global__ void __launch_bounds__(256) k_deg2(const uint32_t* __restrict__ bout,
        const int* __restrict__ gbase, int* __restrict__ deg,
        int* __restrict__ psum, int N) {
    __shared__ int cnt[256];
    __shared__ int red[256];
    int t = threadIdx.x, b = blockIdx.x;
    cnt[t] = 0;
    __syncthreads();
    int s = gbase[b], epos = gbase[b + 1];
    for (int i = s + t; i < epos; i += 256)
        atomicAdd(&cnt[bout[i] & 255], 1);
    __syncthreads();
    int n = b * 256 + t;
    int d = cnt[t];
    if (n < N) deg[n] = d;
    red[t] = (n < N) ? ((d + 7) & ~7) : 0;
    __syncthreads();
    for (int o = 128; o > 0; o >>= 1) {
        if (t < o) red[t] += red[t + o];
        __syncthreads();
    }
    if (t == 0) psum[b] = red[0];
}

// offs (self-computed block prefix over psum; nb <= 256) + dis/diag; last block
// writes offs[N].
__global__ void k_offs(const int* __restrict__ deg, const int* __restrict__ psum,
                       int* __restrict__ offs,
                       const int* __restrict__ batch, const float* __restrict__ lam,
                       float* __restrict__ dis, float* __restrict__ diag,
                       int N, int nb) {
    __shared__ int pre[256];
    __shared__ int sh[256];
    int t = threadIdx.x, b = blockIdx.x;
    pre[t] = (t < b) ? psum[t] : 0;
    __syncthreads();
    for (int o = 128; o > 0; o >>= 1) {
        if (t < o) pre[t] += pre[t + o];
        __syncthreads();
    }
    int base = pre[0];
    __syncthreads();
    int idx = b * 256 + t;
    int d = idx < N ? deg[idx] : 0;
    int v = (d + 7) & ~7;
    sh[t] = v;
    __syncthreads();
    for (int o = 1; o < 256; o <<= 1) {
        int u = (t >= o) ? sh[t - o] : 0;
        __syncthreads();
        sh[t] += u;
        __syncthreads();
    }
    if (idx < N) {
        offs[idx] = base + sh[t] - v;
        dis[idx] = d > 0 ? rsqrtf((float)d) : 0.f;
        diag[idx] = 2.f / lam[batch[idx]] - 1.f;
    }
    if (b == nb - 1 && t == 255) offs[N] = base + sh[255];
}

// final CSR scatter (bucket-local) + self-padding with sentinel col=N
__global__ void __launch_bounds__(256) k_csr2(const uint32_t* __restrict__ bout,
        const int* __restrict__ gbase, const int* __restrict__ offs,
        uint16_t* __restrict__ csr, int N) {
    __shared__ int cur[256];
    int t = threadIdx.x, b = blockIdx.x;
    int n = b * 256 + t;
    int o0 = n < N ? offs[n] : 0;
    cur[t] = o0;
    __syncthreads();
    int s = gbase[b], epos = gbase[b + 1];
    for (int i = s + t; i < epos; i += 256) {
        uint32_t v = bout[i];
        int p = atomicAdd(&cur[v & 255], 1);
        csr[p] = (uint16_t)(v >> 8);
    }
    __syncthreads();
    if (n < N) {
        int e = cur[t];
        int pe = o0 + ((e - o0 + 7) & ~7);
        for (int p = e; p < pe; p++) csr[p] = (uint16_t)N;
    }
}

// W1,W2 [5][128][128] fp32 -> Wt bf16 [128 out][640 kk]; fused pair
__global__ void k_prepw(const float* __restrict__ W1, uint16_t* __restrict__ Wt1,
                        const float* __restrict__ W2, uint16_t* __restrict__ Wt2) {
    int i = blockIdx.x * blockDim.x + threadIdx.x;
    const float* W = W1; uint16_t* Wt = Wt1;
    if (i >= 128 * 640) { i -= 128 * 640; W = W2; Wt = Wt2; }
    int o = i / 640, kk = i % 640;
    Wt[(size_t)o * 640 + kk] = f_to_bf16(W[(size_t)kk * 128 + o]);
}

// x fp32 [N][128] -> slot 0: bf16 row + int8 row + mS/scq
__global__ void __launch_bounds__(256) k_castx(const float* __restrict__ x,
        uint16_t* __restrict__ Txb, int8_t* __restrict__ Txq,
        const float* __restrict__ dis, float* __restrict__ mS,
        float* __restrict__ scq, int N) {
    int n = (blockIdx.x * blockDim.x + threadIdx.x) >> 6;
    int lane = threadIdx.x & 63;
    if (n >= N) return;
    float2 v = ((const float2*)x)[(size_t)n * 64 + lane];
    uint32_t p = (uint32_t)f_to_bf16(v.x) | ((uint32_t)f_to_bf16(v.y) << 16);
    __builtin_nontemporal_store(p, &((uint32_t*)Txb)[(size_t)n * 320 + lane]);
    float m = fmaxf(fabsf(v.x), fabsf(v.y));
    for (int o = 1; o < 64; o <<= 1) m = fmaxf(m, __shfl_xor(m, o));
    float inv = m > 0.f ? 127.f / m : 0.f;
    int qx = (int)rintf(v.x * inv), qy = (int)rintf(v.y * inv);
    uint16_t qp = (uint16_t)((qx & 0xff) | ((qy & 0xff) << 8));
    *(uint16_t*)(Txq + (size_t)n * 640 + 2 * lane) = qp;
    if (lane == 0) {
        float sc = m > 0.f ? m * (1.f / 127.f) : 0.f;
        mS[n] = sc * dis[n];
        scq[n] = sc;
    }
}

// dst = alpha*(gather + diag*src) - (use_prev ? prev : 0)  [full-int8 recurrence]
__global__ void __launch_bounds__(256) k_lhat(
        int8_t* __restrict__ Txq, uint16_t* __restrict__ Txb,
        const int* __restrict__ offs, const uint16_t* __restrict__ csr,
        const float* __restrict__ diag, const float* __restrict__ dis,
        float* __restrict__ mS, float* __restrict__ scq, int N,
        int src, int dst, int prev, float alpha, int use_prev) {
    int n = (blockIdx.x * blockDim.x + threadIdx.x) >> 6;
    int lane = threadIdx.x & 63;
    if (n >= N) return;
    int beg = offs[n], end = offs[n + 1];          // padded: multiple of 8
    float dgn = diag[n], dn = dis[n];
    float aS = -alpha * dn * (dgn + 1.0f);
    const float* mSrc = mS + (size_t)src * (N + 1);
    const int8_t* qbase = Txq + src * 128 + 2 * lane;
    float ax = 0.f, ay = 0.f;
    for (int e = beg; e < end; e += 8) {
        uint4 cw = *(const uint4*)(csr + e);
        int cc[8] = { (int)(cw.x & 0xffff), (int)(cw.x >> 16),
                      (int)(cw.y & 0xffff), (int)(cw.y >> 16),
                      (int)(cw.z & 0xffff), (int)(cw.z >> 16),
                      (int)(cw.w & 0xffff), (int)(cw.w >> 16) };
        float mm[8];
        uint16_t qv[8];
#pragma unroll
        for (int u = 0; u < 8; u++) mm[u] = mSrc[cc[u]];
#pragma unroll
        for (int u = 0; u < 8; u++)
            qv[u] = *(const uint16_t*)(qbase + (size_t)cc[u] * 640);
#pragma unroll
        for (int u = 0; u < 8; u++) {
            float f = aS * mm[u];
            ax = fmaf(f, (float)(int)(int8_t)(qv[u] & 0xff), ax);
            ay = fmaf(f, (float)(int)(int8_t)(qv[u] >> 8), ay);
        }
    }
    {
        uint16_t qsv = *(const uint16_t*)(Txq + (size_t)n * 640 + src * 128 + 2 * lane);
        float ad = alpha * dgn * scq[(size_t)src * (N + 1) + n];
        ax = fmaf(ad, (float)(int)(int8_t)(qsv & 0xff), ax);
        ay = fmaf(ad, (float)(int)(int8_t)(qsv >> 8), ay);
    }
    if (use_prev) {
        uint16_t qpv = *(const uint16_t*)(Txq + (size_t)n * 640 + prev * 128 + 2 * lane);
        float sp = scq[(size_t)prev * (N + 1) + n];
        ax = fmaf(-sp, (float)(int)(int8_t)(qpv & 0xff), ax);
        ay = fmaf(-sp, (float)(int)(int8_t)(qpv >> 8), ay);
    }
    uint32_t outv = (uint32_t)f_to_bf16(ax) | ((uint32_t)f_to_bf16(ay) << 16);
    __builtin_nontemporal_store(outv, &((uint32_t*)Txb)[(size_t)n * 320 + dst * 64 + lane]);
    float m = fmaxf(fabsf(ax), fabsf(ay));
    for (int o = 1; o < 64; o <<= 1) m = fmaxf(m, __shfl_xor(m, o));
    float inv = m > 0.f ? 127.f / m : 0.f;
    int qx = (int)rintf(ax * inv), qy = (int)rintf(ay * inv);
    uint16_t qp = (uint16_t)((qx & 0xff) | ((qy & 0xff) << 8));
    *(uint16_t*)(Txq + (size_t)n * 640 + dst * 128 + 2 * lane) = qp;
    if (lane == 0) {
        float sc = m > 0.f ? m * (1.f / 127.f) : 0.f;
        mS[(size_t)dst * (N + 1) + n] = sc * dn;
        scq[(size_t)dst * (N + 1) + n] = sc;
    }
}

// ---------- GEMM: relu(A[M,Kdim] @ Wt^T + bias), bf16 MFMA, BM=64 tile ----------
// BM=64 -> 782 blocks (vs 391): kills the 1.5-round tail; 27.6KB LDS allows
// multiple blocks/CU co-resident to hide barrier drains.
#define BM 64
#define BK 64
#define LDT 72
#define LDC 132

__global__ void __launch_bounds__(256) k_gemm(
        const uint16_t* __restrict__ A, int lda,
        const uint16_t* __restrict__ Bt,
        const float* __restrict__ bias,
        uint16_t* __restrict__ out2b,              // bf16 slot0 (stride 640) or null
        int8_t* __restrict__ out2q,                // int8 slot0 (stride 640) or null
        const float* __restrict__ dis, float* __restrict__ mS,
        float* __restrict__ scq,
        float* __restrict__ pooled,                // fused pool accum or null
        const int* __restrict__ batch,
        int M, int Kdim) {
    __shared__ uint16_t smem[BM * LDT + 128 * LDT];   // 13824 u16 = 27.6KB
    uint16_t* As = smem;                 // 64 x 72
    uint16_t* Bs = smem + BM * LDT;      // 128 x 72
    uint16_t* Ct = smem;                 // reuse: 64 x 132 = 8448 <= 13824
    int t = threadIdx.x;
    int w = t >> 6, lane = t & 63;
    int row0 = blockIdx.x * BM;
    int mrow = (w >> 1) * 32, ncol = (w & 1) * 64;

    // staging: A 64x8=512 chunks (2 reps), B 128x8=1024 chunks (4 reps)
    int ar2[2], akc2[2], br4[4], bkc4[4];
#pragma unroll
    for (int rep = 0; rep < 2; rep++) {
        int d = rep * 256 + t;
        ar2[rep] = d >> 3; akc2[rep] = d & 7;
    }
#pragma unroll
    for (int rep = 0; rep < 4; rep++) {
        int d = rep * 256 + t;
        br4[rep] = d >> 3; bkc4[rep] = d & 7;
    }

    f32x4 acc[2][4];
#pragma unroll
    for (int i = 0; i < 2; i++)
#pragma unroll
        for (int j = 0; j < 4; j++) acc[i][j] = (f32x4){0.f, 0.f, 0.f, 0.f};

    bf16x8 pa[2], pb[4];
#pragma unroll
    for (int rep = 0; rep < 2; rep++) {
        int grow = row0 + ar2[rep];
        bf16x8 va = {0, 0, 0, 0, 0, 0, 0, 0};
        if (grow < M) va = *(const bf16x8*)(A + (size_t)grow * lda + akc2[rep] * 8);
        pa[rep] = va;
    }
#pragma unroll
    for (int rep = 0; rep < 4; rep++)
        pb[rep] = *(const bf16x8*)(Bt + (size_t)br4[rep] * Kdim + bkc4[rep] * 8);

    for (int k0 = 0; k0 < Kdim; k0 += BK) {
#pragma unroll
        for (int rep = 0; rep < 2; rep++)
            *(bf16x8*)(&As[ar2[rep] * LDT + akc2[rep] * 8]) = pa[rep];
#pragma unroll
        for (int rep = 0; rep < 4; rep++)
            *(bf16x8*)(&Bs[br4[rep] * LDT + bkc4[rep] * 8]) = pb[rep];
        __syncthreads();
        int kn = k0 + BK;
        if (kn < Kdim) {
#pragma unroll
            for (int rep = 0; rep < 2; rep++) {
                int grow = row0 + ar2[rep];
                bf16x8 va = {0, 0, 0, 0, 0, 0, 0, 0};
                if (grow < M) va = *(const bf16x8*)(A + (size_t)grow * lda + kn + akc2[rep] * 8);
                pa[rep] = va;
            }
#pragma unroll
            for (int rep = 0; rep < 4; rep++)
                pb[rep] = *(const bf16x8*)(Bt + (size_t)br4[rep] * Kdim + kn + bkc4[rep] * 8);
        }
#pragma unroll
        for (int ks = 0; ks < BK; ks += 32) {
            bf16x8 af[2], bfr[4];
#pragma unroll
            for (int i = 0; i < 2; i++) {
                int r = mrow + i * 16 + (lane & 15);
                af[i] = *(const bf16x8*)(&As[r * LDT + ks + (lane >> 4) * 8]);
            }
#pragma unroll
            for (int j = 0; j < 4; j++) {
                int c = ncol + j * 16 + (lane & 15);
                bfr[j] = *(const bf16x8*)(&Bs[c * LDT + ks + (lane >> 4) * 8]);
            }
#pragma unroll
            for (int i = 0; i < 2; i++)
#pragma unroll
                for (int j = 0; j < 4; j++)
                    acc[i][j] = __builtin_amdgcn_mfma_f32_16x16x32_bf16(af[i], bfr[j], acc[i][j], 0, 0, 0);
        }
        __syncthreads();
    }

    // bias + relu -> bf16 into LDS
#pragma unroll
    for (int j = 0; j < 4; j++) {
        int c = ncol + j * 16 + (lane & 15);
        float bv = bias[c];
#pragma unroll
        for (int i = 0; i < 2; i++) {
            int rloc = mrow + i * 16 + (lane >> 4) * 4;
#pragma unroll
            for (int r = 0; r < 4; r++) {
                float v = acc[i][j][r] + bv;
                v = v > 0.f ? v : 0.f;
                Ct[(rloc + r) * LDC + c] = f_to_bf16(v);
            }
        }
    }
    __syncthreads();

    if (out2b) {
        // 64 rows x 16 chunks = 1024 chunks -> 4 reps
#pragma unroll
        for (int rep = 0; rep < 4; rep++) {
            int d = rep * 256 + t;
            int r = d >> 4, c8 = (d & 15) * 8;
            int grow = row0 + r;
            if (grow < M) {
                bf16x8 v = *(const bf16x8*)(&Ct[r * LDC + c8]);
                *(bf16x8*)(out2b + (size_t)grow * 640 + c8) = v;
            }
        }
    }
    if (out2q && t < 128) {
        int r = t >> 1, half = t & 1;
        int grow = row0 + r;
        float vmax = 0.f;
        for (int j = 0; j < 32; j++) {
            uint32_t u = *(const uint32_t*)(&Ct[r * LDC + half * 64 + j * 2]);
            vmax = fmaxf(vmax, fmaxf(fabsf(bf16lo_to_f(u)), fabsf(bf16hi_to_f(u))));
        }
        vmax = fmaxf(vmax, __shfl_xor(vmax, 1));
        if (grow < M) {
            float inv = vmax > 0.f ? 127.f / vmax : 0.f;
            for (int j0 = 0; j0 < 16; j0++) {
                uint32_t u0 = *(const uint32_t*)(&Ct[r * LDC + half * 64 + j0 * 4]);
                uint32_t u1 = *(const uint32_t*)(&Ct[r * LDC + half * 64 + j0 * 4 + 2]);
                int q0 = (int)rintf(bf16lo_to_f(u0) * inv);
                int q1 = (int)rintf(bf16hi_to_f(u0) * inv);
                int q2 = (int)rintf(bf16lo_to_f(u1) * inv);
                int q3 = (int)rintf(bf16hi_to_f(u1) * inv);
                uint32_t pk = (q0 & 0xff) | ((q1 & 0xff) << 8) |
                              ((q2 & 0xff) << 16) | ((uint32_t)(q3 & 0xff) << 24);
                *(uint32_t*)(out2q + (size_t)grow * 640 + half * 64 + j0 * 4) = pk;
            }
            if (half == 0) {
                float sc = vmax > 0.f ? vmax * (1.f / 127.f) : 0.f;
                mS[grow] = sc * dis[grow];
                scq[grow] = sc;
            }
        }
    }
    if (pooled) {
        // thread t: feature f=t&127, rows [(t>>7)*32, +32); batch sorted
        int f = t & 127, r0 = (t >> 7) * 32;
        float accp = 0.f;
        int curb = -1;
        for (int r = r0; r < r0 + 32; ++r) {
            int grow = row0 + r;
            if (grow >= M) break;
            int b = batch[grow];
            if (b != curb) {
                if (curb >= 0) atomicAdd(&pooled[curb * 128 + f], accp);
                accp = 0.f; curb = b;
            }
            accp += __uint_as_float(((uint32_t)Ct[r * LDC + f]) << 16);
        }
        if (curb >= 0) atomicAdd(&pooled[curb * 128 + f], accp);
    }
}

// ---------- final linear (counts via binary search on sorted batch) ----------
__global__ void k_final(const float* __restrict__ pooled, const int* __restrict__ batch,
                        const float* __restrict__ Wlin, const float* __restrict__ blin,
                        float* __restrict__ out, int N, int B_, int C_) {
    __shared__ int cnt[64];
    int t = threadIdx.x;
    if (t < B_) {
        auto lb = [&](int v) {
            int lo = 0, hi = N;
            while (lo < hi) {
                int mid = (lo + hi) >> 1;
                if (batch[mid] < v) lo = mid + 1; else hi = mid;
            }
            return lo;
        };
        cnt[t] = lb(t + 1) - lb(t);
    }
    __syncthreads();
    if (t < B_ * C_) {
        int b = t / C_, c = t % C_;
        float inv = 1.f / fmaxf((float)cnt[b], 1.f);
        float acc = blin[c];
        for (int f = 0; f < 128; ++f) acc += pooled[b * 128 + f] * inv * Wlin[f * C_ + c];
        out[t] = acc;
    }
}

// ---------- launch ----------
extern "C" void kernel_launch(void* const* d_in, const int* in_sizes, int n_in,
                              void* d_out, int out_size, void* d_ws, size_t ws_size,
                              hipStream_t stream) {
    const float* x    = (const float*)d_in[0];
    const int*   edge = (const int*)d_in[1];
    const int*   batch= (const int*)d_in[2];
    const float* lam  = (const float*)d_in[3];
    const float* W1   = (const float*)d_in[4];
    const float* b1   = (const float*)d_in[5];
    const float* W2   = (const float*)d_in[6];
    const float* b2   = (const float*)d_in[7];
    const float* Wlin = (const float*)d_in[8];
    const float* blin = (const float*)d_in[9];
    const int E  = in_sizes[1] / 2;
    const int N  = in_sizes[2];
    const int B_ = in_sizes[3];
    const int* row = edge;
    const int* col = edge + E;

    char* ws = (char*)d_ws;
    size_t off = 0;
    auto take = [&](size_t bytes) -> char* {
        char* p = ws + off;
        off = (off + bytes + 255) & ~(size_t)255;
        return p;
    };
    uint16_t* Txb    = (uint16_t*)take((size_t)N * 640 * 2);
    int8_t*   Txq    = (int8_t*)take((size_t)(N + 1) * 640);
    uint16_t* csr    = (uint16_t*)take(((size_t)E + 8 * (size_t)N) * 2);
    uint32_t* bout   = (uint32_t*)take((size_t)E * 4);
    float*    mS     = (float*)take((size_t)5 * (N + 1) * 4);
    float*    scq    = (float*)take((size_t)5 * (N + 1) * 4);
    int*      deg    = (int*)take((size_t)N * 4);
    int*      offs   = (int*)take((size_t)(N + 1) * 4);
    float*    dis    = (float*)take((size_t)N * 4);
    float*    diag   = (float*)take((size_t)N * 4);
    uint16_t* Wt1    = (uint16_t*)take((size_t)128 * 640 * 2);
    uint16_t* Wt2    = (uint16_t*)take((size_t)128 * 640 * 2);
    float*    pooled = (float*)take((size_t)B_ * 128 * 4);   // 256-aligned size
    int*      bhist  = (int*)take(257 * 4);                  // contiguous after pooled
    int*      gbase  = (int*)take(257 * 4);
    int*      gcur   = (int*)take(257 * 4);
    const int nb = (N + 255) / 256;
    int*      psum   = (int*)take((size_t)nb * 4);

    hipMemsetAsync(pooled, 0, (size_t)B_ * 128 * 4 + 257 * 4, stream);

    k_bhist<<<112, 256, 0, stream>>>(row, bhist, E);
    k_bscan<<<1, 256, 0, stream>>>(bhist, gbase, gcur, mS, nb, N);
    k_bin<<<(E + BINCH - 1) / BINCH, 256, 0, stream>>>(row, col, gcur, bout, E);
    k_deg2<<<nb, 256, 0, stream>>>(bout, gbase, deg, psum, N);
    k_offs<<<nb, 256, 0, stream>>>(deg, psum, offs, batch, lam, dis, diag, N, nb);
    k_csr2<<<nb, 256, 0, stream>>>(bout, gbase, offs, csr, N);
    k_prepw<<<(2 * 128 * 640) / 256, 256, 0, stream>>>(W1, Wt1, W2, Wt2);
    k_castx<<<(N + 3) / 4, 256, 0, stream>>>(x, Txb, Txq, dis, mS, scq, N);

    const int lblocks = (N + 3) / 4;
    const int gblocks = (N + BM - 1) / BM;

    // layer 1
    k_lhat<<<lblocks, 256, 0, stream>>>(Txq, Txb, offs, csr, diag, dis, mS, scq, N, 0, 1, 0, 1.f, 0);
    k_lhat<<<lblocks, 256, 0, stream>>>(Txq, Txb, offs, csr, diag, dis, mS, scq, N, 1, 2, 0, 2.f, 1);
    k_lhat<<<lblocks, 256, 0, stream>>>(Txq, Txb, offs, csr, diag, dis, mS, scq, N, 2, 3, 1, 2.f, 1);
    k_lhat<<<lblocks, 256, 0, stream>>>(Txq, Txb, offs, csr, diag, dis, mS, scq, N, 3, 4, 2, 2.f, 1);
    k_gemm<<<gblocks, 256, 0, stream>>>(Txb, 640, Wt1, b1,
                                        Txb, Txq, dis, mS, scq,
                                        (float*)nullptr, batch, N, 640);

    // layer 2
    k_lhat<<<lblocks, 256, 0, stream>>>(Txq, Txb, offs, csr, diag, dis, mS, scq, N, 0, 1, 0, 1.f, 0);
    k_lhat<<<lblocks, 256, 0, stream>>>(Txq, Txb, offs, csr, diag, dis, mS, scq, N, 1, 2, 0, 2.f, 1);
    k_lhat<<<lblocks, 256, 0, stream>>>(Txq, Txb, offs, csr, diag, dis, mS, scq, N, 2, 3, 1, 2.f, 1);
    k_lhat<<<lblocks, 256, 0, stream>>>(Txq, Txb, offs, csr, diag, dis, mS, scq, N, 3, 4, 2, 2.f, 1);
    k_gemm<<<gblocks, 256, 0, stream>>>(Txb, 640, Wt2, b2,
                                        (uint16_t*)nullptr, (int8_t*)nullptr, dis, mS, scq,
                                        pooled, batch, N, 640);

    k_final<<<1, 128, 0, stream>>>(pooled, batch, Wlin, blin, (float*)d_out, N, B_, 10);
}

// Round 15
// 480.812 us; speedup vs baseline: 1.0290x; 1.0290x over previous
//
#include <hip/hip_runtime.h>
#include <hip/hip_bf16.h>
#include <stdint.h>

// ---------- helpers ----------
typedef __attribute__((ext_vector_type(8))) short bf16x8;
typedef __attribute__((ext_vector_type(4))) float f32x4;

__device__ __forceinline__ float bf16lo_to_f(uint32_t u) { return __uint_as_float(u << 16); }
__device__ __forceinline__ float bf16hi_to_f(uint32_t u) { return __uint_as_float(u & 0xffff0000u); }
__device__ __forceinline__ uint16_t f_to_bf16(float f) {
    uint32_t u = __float_as_uint(f);
    uint32_t r = u + 0x7fff + ((u >> 16) & 1);   // round-to-nearest-even
    return (uint16_t)(r >> 16);
}

// Layouts:
//  Txb : bf16 [N][640]  -- GEMM A operand ONLY (write-only in lhat, nontemporal)
//  Txq : int8 [N+1][640] -- gather + recurrence state; row slot = 128B = 1 line
//  mS  : f32 [5][N+1]  dis[n]*rowscale (gather weights); sentinel row N = 0
//  scq : f32 [5][N+1]  plain rowscale (self diag/prev dequant)
//  csr : u16 [E + 8N]  col only; per-node region padded to x8 with sentinel N

#define BINCH 4096

__global__ void __launch_bounds__(256) k_bhist(const int* __restrict__ row,
                                               int* __restrict__ bhist, int E) {
    __shared__ int sh[256];
    int t = threadIdx.x;
    sh[t] = 0;
    __syncthreads();
    int stride = gridDim.x * blockDim.x;
    for (int e = blockIdx.x * blockDim.x + t; e < E; e += stride)
        atomicAdd(&sh[row[e] >> 8], 1);
    __syncthreads();
    if (sh[t]) atomicAdd(&bhist[t], sh[t]);
}

// scan bucket counts -> gbase/gcur; also zero mS sentinels
__global__ void k_bscan(const int* __restrict__ bhist, int* __restrict__ gbase,
                        int* __restrict__ gcur, float* __restrict__ mS, int nbk, int N) {
    __shared__ int sh[256];
    int t = threadIdx.x;
    int v = t < nbk ? bhist[t] : 0;
    sh[t] = v;
    __syncthreads();
    for (int o = 1; o < 256; o <<= 1) {
        int u = (t >= o) ? sh[t - o] : 0;
        __syncthreads();
        sh[t] += u;
        __syncthreads();
    }
    gbase[t] = sh[t] - v;
    gcur[t] = sh[t] - v;
    if (t == 255) gbase[256] = sh[255];
    if (t < 5) mS[(size_t)t * (N + 1) + N] = 0.f;
}

// bin edges into bucket-sorted list; entry = (row&255) | (col<<8)
__global__ void __launch_bounds__(256) k_bin(const int* __restrict__ row,
        const int* __restrict__ col, int* __restrict__ gcur,
        uint32_t* __restrict__ bout, int E) {
    __shared__ uint32_t stage[BINCH];
    __shared__ int hist[256], hscan[256], hcur[256], gofs[256];
    int t = threadIdx.x;
    int e0 = blockIdx.x * BINCH;
    int ecnt = min(BINCH, E - e0);
    hist[t] = 0;
    __syncthreads();
    for (int i = t; i < ecnt; i += 256)
        atomicAdd(&hist[row[e0 + i] >> 8], 1);
    __syncthreads();
    int v = hist[t];
    hscan[t] = v;
    __syncthreads();
    for (int o = 1; o < 256; o <<= 1) {
        int u = (t >= o) ? hscan[t - o] : 0;
        __syncthreads();
        hscan[t] += u;
        __syncthreads();
    }
    hcur[t] = hscan[t] - v;
    __syncthreads();
    for (int i = t; i < ecnt; i += 256) {
        int r = row[e0 + i];
        int p = atomicAdd(&hcur[r >> 8], 1);
        stage[p] = (uint32_t)(r & 255) | ((uint32_t)col[e0 + i] << 8);
    }
    __syncthreads();
    if (v > 0) gofs[t] = atomicAdd(&gcur[t], v);
    __syncthreads();
    for (int i = t; i < ecnt; i += 256) {
        int lo = 0, hi = 255;
        while (lo < hi) { int mid = (lo + hi) >> 1; if (hscan[mid] > i) hi = mid; else lo = mid + 1; }
        int b = lo;
        int local = i - (hscan[b] - hist[b]);
        bout[gofs[b] + local] = stage[i];
    }
}

// per-node degree from bucket lists, FUSED with padded per-block sum (psum)
__global__ void __launch_bounds__(256) k_deg2(const uint32_t* __restrict__ bout,
        const int* __restrict__ gbase, int* __restrict__ deg,
        int* __restrict__ psum, int N) {
    __shared__ int cnt[256];
    __shared__ int red[256];
    int t = threadIdx.x, b = blockIdx.x;
    cnt[t] = 0;
    __syncthreads();
    int s = gbase[b], epos = gbase[b + 1];
    for (int i = s + t; i < epos; i += 256)
        atomicAdd(&cnt[bout[i] & 255], 1);
    __syncthreads();
    int n = b * 256 + t;
    int d = cnt[t];
    if (n < N) deg[n] = d;
    red[t] = (n < N) ? ((d + 7) & ~7) : 0;
    __syncthreads();
    for (int o = 128; o > 0; o >>= 1) {
        if (t < o) red[t] += red[t + o];
        __syncthreads();
    }
    if (t == 0) psum[b] = red[0];
}

// offs (self-computed block prefix over psum; nb <= 256) + dis/diag; last block
// writes offs[N].
__global__ void k_offs(const int* __restrict__ deg, const int* __restrict__ psum,
                       int* __restrict__ offs,
                       const int* __restrict__ batch, const float* __restrict__ lam,
                       float* __restrict__ dis, float* __restrict__ diag,
                       int N, int nb) {
    __shared__ int pre[256];
    __shared__ int sh[256];
    int t = threadIdx.x, b = blockIdx.x;
    pre[t] = (t < b) ? psum[t] : 0;
    __syncthreads();
    for (int o = 128; o > 0; o >>= 1) {
        if (t < o) pre[t] += pre[t + o];
        __syncthreads();
    }
    int base = pre[0];
    __syncthreads();
    int idx = b * 256 + t;
    int d = idx < N ? deg[idx] : 0;
    int v = (d + 7) & ~7;
    sh[t] = v;
    __syncthreads();
    for (int o = 1; o < 256; o <<= 1) {
        int u = (t >= o) ? sh[t - o] : 0;
        __syncthreads();
        sh[t] += u;
        __syncthreads();
    }
    if (idx < N) {
        offs[idx] = base + sh[t] - v;
        dis[idx] = d > 0 ? rsqrtf((float)d) : 0.f;
        diag[idx] = 2.f / lam[batch[idx]] - 1.f;
    }
    if (b == nb - 1 && t == 255) offs[N] = base + sh[255];
}

// final CSR scatter (bucket-local) + self-padding with sentinel col=N
__global__ void __launch_bounds__(256) k_csr2(const uint32_t* __restrict__ bout,
        const int* __restrict__ gbase, const int* __restrict__ offs,
        uint16_t* __restrict__ csr, int N) {
    __shared__ int cur[256];
    int t = threadIdx.x, b = blockIdx.x;
    int n = b * 256 + t;
    int o0 = n < N ? offs[n] : 0;
    cur[t] = o0;
    __syncthreads();
    int s = gbase[b], epos = gbase[b + 1];
    for (int i = s + t; i < epos; i += 256) {
        uint32_t v = bout[i];
        int p = atomicAdd(&cur[v & 255], 1);
        csr[p] = (uint16_t)(v >> 8);
    }
    __syncthreads();
    if (n < N) {
        int e = cur[t];
        int pe = o0 + ((e - o0 + 7) & ~7);
        for (int p = e; p < pe; p++) csr[p] = (uint16_t)N;
    }
}

// W1,W2 [5][128][128] fp32 -> Wt bf16 [128 out][640 kk]; fused pair
__global__ void k_prepw(const float* __restrict__ W1, uint16_t* __restrict__ Wt1,
                        const float* __restrict__ W2, uint16_t* __restrict__ Wt2) {
    int i = blockIdx.x * blockDim.x + threadIdx.x;
    const float* W = W1; uint16_t* Wt = Wt1;
    if (i >= 128 * 640) { i -= 128 * 640; W = W2; Wt = Wt2; }
    int o = i / 640, kk = i % 640;
    Wt[(size_t)o * 640 + kk] = f_to_bf16(W[(size_t)kk * 128 + o]);
}

// x fp32 [N][128] -> slot 0: bf16 row + int8 row + mS/scq
__global__ void __launch_bounds__(256) k_castx(const float* __restrict__ x,
        uint16_t* __restrict__ Txb, int8_t* __restrict__ Txq,
        const float* __restrict__ dis, float* __restrict__ mS,
        float* __restrict__ scq, int N) {
    int n = (blockIdx.x * blockDim.x + threadIdx.x) >> 6;
    int lane = threadIdx.x & 63;
    if (n >= N) return;
    float2 v = ((const float2*)x)[(size_t)n * 64 + lane];
    uint32_t p = (uint32_t)f_to_bf16(v.x) | ((uint32_t)f_to_bf16(v.y) << 16);
    __builtin_nontemporal_store(p, &((uint32_t*)Txb)[(size_t)n * 320 + lane]);
    float m = fmaxf(fabsf(v.x), fabsf(v.y));
    for (int o = 1; o < 64; o <<= 1) m = fmaxf(m, __shfl_xor(m, o));
    float inv = m > 0.f ? 127.f / m : 0.f;
    int qx = (int)rintf(v.x * inv), qy = (int)rintf(v.y * inv);
    uint16_t qp = (uint16_t)((qx & 0xff) | ((qy & 0xff) << 8));
    *(uint16_t*)(Txq + (size_t)n * 640 + 2 * lane) = qp;
    if (lane == 0) {
        float sc = m > 0.f ? m * (1.f / 127.f) : 0.f;
        mS[n] = sc * dis[n];
        scq[n] = sc;
    }
}

// dst = alpha*(gather + diag*src) - (use_prev ? prev : 0)  [full-int8 recurrence]
__global__ void __launch_bounds__(256) k_lhat(
        int8_t* __restrict__ Txq, uint16_t* __restrict__ Txb,
        const int* __restrict__ offs, const uint16_t* __restrict__ csr,
        const float* __restrict__ diag, const float* __restrict__ dis,
        float* __restrict__ mS, float* __restrict__ scq, int N,
        int src, int dst, int prev, float alpha, int use_prev) {
    int n = (blockIdx.x * blockDim.x + threadIdx.x) >> 6;
    int lane = threadIdx.x & 63;
    if (n >= N) return;
    int beg = offs[n], end = offs[n + 1];          // padded: multiple of 8
    float dgn = diag[n], dn = dis[n];
    float aS = -alpha * dn * (dgn + 1.0f);
    const float* mSrc = mS + (size_t)src * (N + 1);
    const int8_t* qbase = Txq + src * 128 + 2 * lane;
    float ax = 0.f, ay = 0.f;
    for (int e = beg; e < end; e += 8) {
        uint4 cw = *(const uint4*)(csr + e);
        int cc[8] = { (int)(cw.x & 0xffff), (int)(cw.x >> 16),
                      (int)(cw.y & 0xffff), (int)(cw.y >> 16),
                      (int)(cw.z & 0xffff), (int)(cw.z >> 16),
                      (int)(cw.w & 0xffff), (int)(cw.w >> 16) };
        float mm[8];
        uint16_t qv[8];
#pragma unroll
        for (int u = 0; u < 8; u++) mm[u] = mSrc[cc[u]];
#pragma unroll
        for (int u = 0; u < 8; u++)
            qv[u] = *(const uint16_t*)(qbase + (size_t)cc[u] * 640);
#pragma unroll
        for (int u = 0; u < 8; u++) {
            float f = aS * mm[u];
            ax = fmaf(f, (float)(int)(int8_t)(qv[u] & 0xff), ax);
            ay = fmaf(f, (float)(int)(int8_t)(qv[u] >> 8), ay);
        }
    }
    {
        uint16_t qsv = *(const uint16_t*)(Txq + (size_t)n * 640 + src * 128 + 2 * lane);
        float ad = alpha * dgn * scq[(size_t)src * (N + 1) + n];
        ax = fmaf(ad, (float)(int)(int8_t)(qsv & 0xff), ax);
        ay = fmaf(ad, (float)(int)(int8_t)(qsv >> 8), ay);
    }
    if (use_prev) {
        uint16_t qpv = *(const uint16_t*)(Txq + (size_t)n * 640 + prev * 128 + 2 * lane);
        float sp = scq[(size_t)prev * (N + 1) + n];
        ax = fmaf(-sp, (float)(int)(int8_t)(qpv & 0xff), ax);
        ay = fmaf(-sp, (float)(int)(int8_t)(qpv >> 8), ay);
    }
    uint32_t outv = (uint32_t)f_to_bf16(ax) | ((uint32_t)f_to_bf16(ay) << 16);
    __builtin_nontemporal_store(outv, &((uint32_t*)Txb)[(size_t)n * 320 + dst * 64 + lane]);
    float m = fmaxf(fabsf(ax), fabsf(ay));
    for (int o = 1; o < 64; o <<= 1) m = fmaxf(m, __shfl_xor(m, o));
    float inv = m > 0.f ? 127.f / m : 0.f;
    int qx = (int)rintf(ax * inv), qy = (int)rintf(ay * inv);
    uint16_t qp = (uint16_t)((qx & 0xff) | ((qy & 0xff) << 8));
    *(uint16_t*)(Txq + (size_t)n * 640 + dst * 128 + 2 * lane) = qp;
    if (lane == 0) {
        float sc = m > 0.f ? m * (1.f / 127.f) : 0.f;
        mS[(size_t)dst * (N + 1) + n] = sc * dn;
        scq[(size_t)dst * (N + 1) + n] = sc;
    }
}

// ---------- GEMM: relu(A[M,Kdim] @ Wt^T + bias), bf16 MFMA, BM=128 tile ----------
#define BM 128
#define BK 64
#define LDT 72
#define LDC 132

__global__ void __launch_bounds__(256) k_gemm(
        const uint16_t* __restrict__ A, int lda,
        const uint16_t* __restrict__ Bt,
        const float* __restrict__ bias,
        uint16_t* __restrict__ out2b,              // bf16 slot0 (stride 640) or null
        int8_t* __restrict__ out2q,                // int8 slot0 (stride 640) or null
        const float* __restrict__ dis, float* __restrict__ mS,
        float* __restrict__ scq,
        float* __restrict__ pooled,                // fused pool accum or null
        const int* __restrict__ batch,
        int M, int Kdim) {
    __shared__ uint16_t smem[BM * LDT + 128 * LDT];
    uint16_t* As = smem;
    uint16_t* Bs = smem + BM * LDT;
    uint16_t* Ct = smem;
    int t = threadIdx.x;
    int w = t >> 6, lane = t & 63;
    int row0 = blockIdx.x * BM;
    int mrow = (w >> 1) * 64, ncol = (w & 1) * 64;

    int ar[4], akc[4];
#pragma unroll
    for (int rep = 0; rep < 4; rep++) {
        int d = rep * 256 + t;
        ar[rep] = d >> 3; akc[rep] = d & 7;
    }

    f32x4 acc[4][4];
#pragma unroll
    for (int i = 0; i < 4; i++)
#pragma unroll
        for (int j = 0; j < 4; j++) acc[i][j] = (f32x4){0.f, 0.f, 0.f, 0.f};

    bf16x8 pa[4], pb[4];
#pragma unroll
    for (int rep = 0; rep < 4; rep++) {
        int grow = row0 + ar[rep];
        bf16x8 va = {0, 0, 0, 0, 0, 0, 0, 0};
        if (grow < M) va = *(const bf16x8*)(A + (size_t)grow * lda + akc[rep] * 8);
        pa[rep] = va;
        pb[rep] = *(const bf16x8*)(Bt + (size_t)ar[rep] * Kdim + akc[rep] * 8);
    }

    for (int k0 = 0; k0 < Kdim; k0 += BK) {
#pragma unroll
        for (int rep = 0; rep < 4; rep++) {
            *(bf16x8*)(&As[ar[rep] * LDT + akc[rep] * 8]) = pa[rep];
            *(bf16x8*)(&Bs[ar[rep] * LDT + akc[rep] * 8]) = pb[rep];
        }
        __syncthreads();
        int kn = k0 + BK;
        if (kn < Kdim) {
#pragma unroll
            for (int rep = 0; rep < 4; rep++) {
                int grow = row0 + ar[rep];
                bf16x8 va = {0, 0, 0, 0, 0, 0, 0, 0};
                if (grow < M) va = *(const bf16x8*)(A + (size_t)grow * lda + kn + akc[rep] * 8);
                pa[rep] = va;
                pb[rep] = *(const bf16x8*)(Bt + (size_t)ar[rep] * Kdim + kn + akc[rep] * 8);
            }
        }
#pragma unroll
        for (int ks = 0; ks < BK; ks += 32) {
            bf16x8 af[4], bfr[4];
#pragma unroll
            for (int i = 0; i < 4; i++) {
                int r = mrow + i * 16 + (lane & 15);
                af[i] = *(const bf16x8*)(&As[r * LDT + ks + (lane >> 4) * 8]);
            }
#pragma unroll
            for (int j = 0; j < 4; j++) {
                int c = ncol + j * 16 + (lane & 15);
                bfr[j] = *(const bf16x8*)(&Bs[c * LDT + ks + (lane >> 4) * 8]);
            }
#pragma unroll
            for (int i = 0; i < 4; i++)
#pragma unroll
                for (int j = 0; j < 4; j++)
                    acc[i][j] = __builtin_amdgcn_mfma_f32_16x16x32_bf16(af[i], bfr[j], acc[i][j], 0, 0, 0);
        }
        __syncthreads();
    }

    // bias + relu -> bf16 into LDS
#pragma unroll
    for (int j = 0; j < 4; j++) {
        int c = ncol + j * 16 + (lane & 15);
        float bv = bias[c];
#pragma unroll
        for (int i = 0; i < 4; i++) {
            int rloc = mrow + i * 16 + (lane >> 4) * 4;
#pragma unroll
            for (int r = 0; r < 4; r++) {
                float v = acc[i][j][r] + bv;
                v = v > 0.f ? v : 0.f;
                Ct[(rloc + r) * LDC + c] = f_to_bf16(v);
            }
        }
    }
    __syncthreads();

    if (out2b) {
#pragma unroll
        for (int rep = 0; rep < 8; rep++) {
            int d = rep * 256 + t;
            int r = d >> 4, c8 = (d & 15) * 8;
            int grow = row0 + r;
            if (grow < M) {
                bf16x8 v = *(const bf16x8*)(&Ct[r * LDC + c8]);
                *(bf16x8*)(out2b + (size_t)grow * 640 + c8) = v;
            }
        }
    }
    if (out2q) {
        int r = t >> 1, half = t & 1;
        int grow = row0 + r;
        float vmax = 0.f;
        for (int j = 0; j < 32; j++) {
            uint32_t u = *(const uint32_t*)(&Ct[r * LDC + half * 64 + j * 2]);
            vmax = fmaxf(vmax, fmaxf(fabsf(bf16lo_to_f(u)), fabsf(bf16hi_to_f(u))));
        }
        vmax = fmaxf(vmax, __shfl_xor(vmax, 1));
        if (grow < M) {
            float inv = vmax > 0.f ? 127.f / vmax : 0.f;
            for (int j0 = 0; j0 < 16; j0++) {
                uint32_t u0 = *(const uint32_t*)(&Ct[r * LDC + half * 64 + j0 * 4]);
                uint32_t u1 = *(const uint32_t*)(&Ct[r * LDC + half * 64 + j0 * 4 + 2]);
                int q0 = (int)rintf(bf16lo_to_f(u0) * inv);
                int q1 = (int)rintf(bf16hi_to_f(u0) * inv);
                int q2 = (int)rintf(bf16lo_to_f(u1) * inv);
                int q3 = (int)rintf(bf16hi_to_f(u1) * inv);
                uint32_t pk = (q0 & 0xff) | ((q1 & 0xff) << 8) |
                              ((q2 & 0xff) << 16) | ((uint32_t)(q3 & 0xff) << 24);
                *(uint32_t*)(out2q + (size_t)grow * 640 + half * 64 + j0 * 4) = pk;
            }
            if (half == 0) {
                float sc = vmax > 0.f ? vmax * (1.f / 127.f) : 0.f;
                mS[grow] = sc * dis[grow];
                scq[grow] = sc;
            }
        }
    }
    if (pooled) {
        // fused mean-pool accumulation: thread t covers feature f = t&127,
        // rows [ (t>>7)*64, +64 ); batch sorted -> segmented flush
        int f = t & 127, r0 = (t >> 7) * 64;
        float accp = 0.f;
        int curb = -1;
        for (int r = r0; r < r0 + 64; ++r) {
            int grow = row0 + r;
            if (grow >= M) break;
            int b = batch[grow];
            if (b != curb) {
                if (curb >= 0) atomicAdd(&pooled[curb * 128 + f], accp);
                accp = 0.f; curb = b;
            }
            accp += __uint_as_float(((uint32_t)Ct[r * LDC + f]) << 16);
        }
        if (curb >= 0) atomicAdd(&pooled[curb * 128 + f], accp);
    }
}

// ---------- final linear (counts via binary search on sorted batch) ----------
__global__ void k_final(const float* __restrict__ pooled, const int* __restrict__ batch,
                        const float* __restrict__ Wlin, const float* __restrict__ blin,
                        float* __restrict__ out, int N, int B_, int C_) {
    __shared__ int cnt[64];
    int t = threadIdx.x;
    if (t < B_) {
        auto lb = [&](int v) {
            int lo = 0, hi = N;
            while (lo < hi) {
                int mid = (lo + hi) >> 1;
                if (batch[mid] < v) lo = mid + 1; else hi = mid;
            }
            return lo;
        };
        cnt[t] = lb(t + 1) - lb(t);
    }
    __syncthreads();
    if (t < B_ * C_) {
        int b = t / C_, c = t % C_;
        float inv = 1.f / fmaxf((float)cnt[b], 1.f);
        float acc = blin[c];
        for (int f = 0; f < 128; ++f) acc += pooled[b * 128 + f] * inv * Wlin[f * C_ + c];
        out[t] = acc;
    }
}

// ---------- launch ----------
extern "C" void kernel_launch(void* const* d_in, const int* in_sizes, int n_in,
                              void* d_out, int out_size, void* d_ws, size_t ws_size,
                              hipStream_t stream) {
    const float* x    = (const float*)d_in[0];
    const int*   edge = (const int*)d_in[1];
    const int*   batch= (const int*)d_in[2];
    const float* lam  = (const float*)d_in[3];
    const float* W1   = (const float*)d_in[4];
    const float* b1   = (const float*)d_in[5];
    const float* W2   = (const float*)d_in[6];
    const float* b2   = (const float*)d_in[7];
    const float* Wlin = (const float*)d_in[8];
    const float* blin = (const float*)d_in[9];
    const int E  = in_sizes[1] / 2;
    const int N  = in_sizes[2];
    const int B_ = in_sizes[3];
    const int* row = edge;
    const int* col = edge + E;

    char* ws = (char*)d_ws;
    size_t off = 0;
    auto take = [&](size_t bytes) -> char* {
        char* p = ws + off;
        off = (off + bytes + 255) & ~(size_t)255;
        return p;
    };
    uint16_t* Txb    = (uint16_t*)take((size_t)N * 640 * 2);
    int8_t*   Txq    = (int8_t*)take((size_t)(N + 1) * 640);
    uint16_t* csr    = (uint16_t*)take(((size_t)E + 8 * (size_t)N) * 2);
    uint32_t* bout   = (uint32_t*)take((size_t)E * 4);
    float*    mS     = (float*)take((size_t)5 * (N + 1) * 4);
    float*    scq    = (float*)take((size_t)5 * (N + 1) * 4);
    int*      deg    = (int*)take((size_t)N * 4);
    int*      offs   = (int*)take((size_t)(N + 1) * 4);
    float*    dis    = (float*)take((size_t)N * 4);
    float*    diag   = (float*)take((size_t)N * 4);
    uint16_t* Wt1    = (uint16_t*)take((size_t)128 * 640 * 2);
    uint16_t* Wt2    = (uint16_t*)take((size_t)128 * 640 * 2);
    float*    pooled = (float*)take((size_t)B_ * 128 * 4);   // 256-aligned size
    int*      bhist  = (int*)take(257 * 4);                  // contiguous after pooled
    int*      gbase  = (int*)take(257 * 4);
    int*      gcur   = (int*)take(257 * 4);
    const int nb = (N + 255) / 256;
    int*      psum   = (int*)take((size_t)nb * 4);

    // one fill covers pooled (B_*512 bytes, 256-multiple) + bhist
    hipMemsetAsync(pooled, 0, (size_t)B_ * 128 * 4 + 257 * 4, stream);

    k_bhist<<<112, 256, 0, stream>>>(row, bhist, E);
    k_bscan<<<1, 256, 0, stream>>>(bhist, gbase, gcur, mS, nb, N);
    k_bin<<<(E + BINCH - 1) / BINCH, 256, 0, stream>>>(row, col, gcur, bout, E);
    k_deg2<<<nb, 256, 0, stream>>>(bout, gbase, deg, psum, N);
    k_offs<<<nb, 256, 0, stream>>>(deg, psum, offs, batch, lam, dis, diag, N, nb);
    k_csr2<<<nb, 256, 0, stream>>>(bout, gbase, offs, csr, N);
    k_prepw<<<(2 * 128 * 640) / 256, 256, 0, stream>>>(W1, Wt1, W2, Wt2);
    k_castx<<<(N + 3) / 4, 256, 0, stream>>>(x, Txb, Txq, dis, mS, scq, N);

    const int lblocks = (N + 3) / 4;
    const int gblocks = (N + BM - 1) / BM;

    // layer 1
    k_lhat<<<lblocks, 256, 0, stream>>>(Txq, Txb, offs, csr, diag, dis, mS, scq, N, 0, 1, 0, 1.f, 0);
    k_lhat<<<lblocks, 256, 0, stream>>>(Txq, Txb, offs, csr, diag, dis, mS, scq, N, 1, 2, 0, 2.f, 1);
    k_lhat<<<lblocks, 256, 0, stream>>>(Txq, Txb, offs, csr, diag, dis, mS, scq, N, 2, 3, 1, 2.f, 1);
    k_lhat<<<lblocks, 256, 0, stream>>>(Txq, Txb, offs, csr, diag, dis, mS, scq, N, 3, 4, 2, 2.f, 1);
    k_gemm<<<gblocks, 256, 0, stream>>>(Txb, 640, Wt1, b1,
                                        Txb, Txq, dis, mS, scq,
                                        (float*)nullptr, batch, N, 640);

    // layer 2
    k_lhat<<<lblocks, 256, 0, stream>>>(Txq, Txb, offs, csr, diag, dis, mS, scq, N, 0, 1, 0, 1.f, 0);
    k_lhat<<<lblocks, 256, 0, stream>>>(Txq, Txb, offs, csr, diag, dis, mS, scq, N, 1, 2, 0, 2.f, 1);
    k_lhat<<<lblocks, 256, 0, stream>>>(Txq, Txb, offs, csr, diag, dis, mS, scq, N, 2, 3, 1, 2.f, 1);
    k_lhat<<<lblocks, 256, 0, stream>>>(Txq, Txb, offs, csr, diag, dis, mS, scq, N, 3, 4, 2, 2.f, 1);
    k_gemm<<<gblocks, 256, 0, stream>>>(Txb, 640, Wt2, b2,
                                        (uint16_t*)nullptr, (int8_t*)nullptr, dis, mS, scq,
                                        pooled, batch, N, 640);

    k_final<<<1, 128, 0, stream>>>(pooled, batch, Wlin, blin, (float*)d_out, N, B_, 10);
}